// Round 9
// baseline (2196.900 us; speedup 1.0000x reference)
//
#include <hip/hip_runtime.h>
#include <cstdint>
#include <cstddef>

#define N_NODES 50000
#define N_EDGES 200000
#define N_GRAPHS 2000
#define F_IN 373
#define NEG_SLOPE 0.2f
#define BN_EPS 1e-5f

typedef float f32x4 __attribute__((ext_vector_type(4)));
typedef float f32x2 __attribute__((ext_vector_type(2)));
typedef short s16x8 __attribute__((ext_vector_type(8)));
typedef short s16x4 __attribute__((ext_vector_type(4)));
typedef unsigned int u32x4 __attribute__((ext_vector_type(4)));
typedef unsigned int u32x2 __attribute__((ext_vector_type(2)));

template <int VPT> struct VecT;
template <> struct VecT<2> { using type = f32x2; };
template <> struct VecT<4> { using type = f32x4; };
template <int VPT> struct UVecT;
template <> struct UVecT<2> { using type = u32x2; };
template <> struct UVecT<4> { using type = u32x4; };

static inline int cdiv(long long a, long long b) { return (int)((a + b - 1) / b); }

__device__ __forceinline__ float lrelu(float x) { return x > 0.f ? x : NEG_SLOPE * x; }

__device__ __forceinline__ void atomAddF(float* p, float v) {
#if defined(__HIP_DEVICE_COMPILE__)
  unsafeAtomicAdd(p, v);
#else
  atomicAdd(p, v);
#endif
}

__device__ __forceinline__ unsigned short bf16rne(float f) {
  unsigned u = __float_as_uint(f);
  unsigned r = u + 0x7fffu + ((u >> 16) & 1u);
  return (unsigned short)(r >> 16);
}
__device__ __forceinline__ void split2(float f, unsigned short& hi, unsigned short& lo) {
  hi = bf16rne(f);
  float fh = __uint_as_float(((unsigned)hi) << 16);
  lo = bf16rne(f - fh);
}
__device__ __forceinline__ unsigned packsplit(float f) {
  unsigned short hi, lo;
  split2(f, hi, lo);
  return (((unsigned)hi) << 16) | (unsigned)lo;
}
__device__ __forceinline__ float unpackf(unsigned w) {
  return __uint_as_float(w & 0xffff0000u) + __uint_as_float(w << 16);
}

// fragment-order LDS layout (shorts): elem(row,k) -> (row>>4)*512 + (k>>3)*128
// + (row&15)*8 + (k&7).  Bank aliasing on writes measured irrelevant (r6-r8).
__device__ __forceinline__ int ebase(int row, int k) {
  return ((row >> 4) << 9) + ((k >> 3) << 7) + ((row & 15) << 3) + (k & 7);
}

// ---------------- utility ----------------
__global__ void k_zero(float* p, long long n) {
  long long i = (long long)blockIdx.x * blockDim.x + threadIdx.x;
  if (i < n) p[i] = 0.f;
}
__global__ void k_zero_i(int* p, int n) {
  int i = blockIdx.x * blockDim.x + threadIdx.x;
  if (i < n) p[i] = 0;
}
__global__ void k_deg(int* __restrict__ deg, const int* __restrict__ dst, int e) {
  int i = blockIdx.x * blockDim.x + threadIdx.x;
  if (i < e) atomicAdd(&deg[dst[i]], 1);
}
__global__ void k_dinv(const int* __restrict__ deg, float* __restrict__ dinv, int n) {
  int i = blockIdx.x * blockDim.x + threadIdx.x;
  if (i < n) dinv[i] = rsqrtf((float)deg[i] + 1.0f);
}

__global__ void k_scan(const int* __restrict__ deg, int* __restrict__ rowptr,
                       int* __restrict__ cursor, int n) {
  __shared__ int wsum[16];
  __shared__ int carry_s;
  const int lane = threadIdx.x & 63;
  const int wid = threadIdx.x >> 6;
  if (threadIdx.x == 0) carry_s = 0;
  __syncthreads();
  for (int base = 0; base < n; base += 1024) {
    int i = base + threadIdx.x;
    int v = (i < n) ? deg[i] : 0;
    int s = v;
#pragma unroll
    for (int off = 1; off < 64; off <<= 1) {
      int t = __shfl_up(s, off);
      if (lane >= off) s += t;
    }
    if (lane == 63) wsum[wid] = s;
    __syncthreads();
    if (threadIdx.x == 0) {
      int acc = carry_s;
#pragma unroll
      for (int w = 0; w < 16; w++) { int t = wsum[w]; wsum[w] = acc; acc += t; }
      carry_s = acc;
    }
    __syncthreads();
    if (i < n) { rowptr[i] = wsum[wid] + s - v; cursor[i] = 0; }
    __syncthreads();
  }
  if (threadIdx.x == 0) rowptr[n] = carry_s;
}

__global__ void k_csr_scatter(const int* __restrict__ src, const int* __restrict__ dst,
                              const int* __restrict__ rowptr, int* __restrict__ cursor,
                              int* __restrict__ csr_src, int e) {
  int i = blockIdx.x * blockDim.x + threadIdx.x;
  if (i >= e) return;
  int d = dst[i];
  int pos = rowptr[d] + atomicAdd(&cursor[d], 1);
  csr_src[pos] = src[i];
}

__global__ void k_buildwt(const float* __restrict__ W, int ldW, int col0, int Nsub,
                          int K, int Kpad, unsigned* __restrict__ Wt) {
  int n = blockIdx.x * blockDim.x + threadIdx.x;
  int k = blockIdx.y;
  if (n >= Nsub) return;
  float v = (k < K) ? W[(size_t)k * ldW + col0 + n] : 0.f;
  Wt[(size_t)n * Kpad + k] = packsplit(v);
}

// ---------------- MFMA split-bf16 GEMM: 64x128 tile, in-kernel col loop ----------------
// C[M, Nsub] (ld=ldC, col offset col0) = A[M, K] @ Wt^T   (Wt: [Nsub, Kpad])
// grid = row-bands only (cdiv(M,64)); each block loops ncol = Nsub/128 col tiles,
// restaging A each pass (2nd+ pass hits this CU's L2 -> no cross-XCD refetch).
// amode: 0 = fp32 scalar w/ k<Kact guard; 1 = packed u32 float4; 2 = fp32 float4.
// a_s != null: fuse attention logits (als/ald head-major, head = bn >> lshift).
__global__ __launch_bounds__(256) void k_mfma_gemm(
    const float* __restrict__ Ap, int lda, int amode, int Kact,
    const unsigned* __restrict__ Wt, int Kpad, int ncol,
    float* __restrict__ C, int M, int ldC, int col0,
    const float* __restrict__ a_s, const float* __restrict__ a_d,
    float* __restrict__ als, float* __restrict__ ald, int lshift) {
  __shared__ unsigned short Ah[64 * 32], Al[64 * 32], Bh[128 * 32], Bl[128 * 32];
  const int bm = blockIdx.x * 64;
  const int tid = threadIdx.x;
  const int lane = tid & 63;
  const int wave = tid >> 6;
  const int wm = wave & 1;   // row half (32 rows)
  const int wn = wave >> 1;  // col half (64 cols)

  const int srow = tid >> 3;        // 0..31
  const int skq = (tid & 7) << 2;   // 0,4,...,28
  const int mrow = lane & 15;
  const int rq = (lane >> 4) << 2;

  for (int col = 0; col < ncol; col++) {
    const int bn = col * 128;
    f32x4 acc[2][4];
#pragma unroll
    for (int i = 0; i < 2; i++)
#pragma unroll
      for (int j = 0; j < 4; j++) acc[i][j] = (f32x4){0.f, 0.f, 0.f, 0.f};

    for (int k0 = 0; k0 < Kpad; k0 += 32) {
      // ---- stage A: 64 rows (L2-hot after first col pass) ----
#pragma unroll
      for (int i = 0; i < 2; i++) {
        int row = i * 32 + srow;
        int grow = bm + row;
        unsigned short hv[4], lv[4];
        if (amode == 1) {
          u32x4 v = (grow < M) ? *(const u32x4*)((const unsigned*)Ap + (size_t)grow * lda + k0 + skq)
                               : (u32x4){0u, 0u, 0u, 0u};
#pragma unroll
          for (int u = 0; u < 4; u++) { hv[u] = (unsigned short)(v[u] >> 16); lv[u] = (unsigned short)(v[u] & 0xffffu); }
        } else if (amode == 2) {
          f32x4 v = (grow < M) ? *(const f32x4*)(Ap + (size_t)grow * lda + k0 + skq)
                               : (f32x4){0.f, 0.f, 0.f, 0.f};
#pragma unroll
          for (int u = 0; u < 4; u++) split2(v[u], hv[u], lv[u]);
        } else {
          const float* ap = Ap + (size_t)grow * lda;
#pragma unroll
          for (int u = 0; u < 4; u++) {
            int kc = k0 + skq + u;
            float f = (grow < M && kc < Kact) ? ap[kc] : 0.f;
            split2(f, hv[u], lv[u]);
          }
        }
        int eb = ebase(row, skq);
        *(s16x4*)&Ah[eb] = *(s16x4*)hv;
        *(s16x4*)&Al[eb] = *(s16x4*)lv;
      }
      // ---- stage B: 128 Wt rows of this col tile ----
#pragma unroll
      for (int i = 0; i < 4; i++) {
        int row = i * 32 + srow;
        u32x4 v = *(const u32x4*)(Wt + (size_t)(bn + row) * Kpad + k0 + skq);
        unsigned short hv[4], lv[4];
#pragma unroll
        for (int u = 0; u < 4; u++) { hv[u] = (unsigned short)(v[u] >> 16); lv[u] = (unsigned short)(v[u] & 0xffffu); }
        int eb = ebase(row, skq);
        *(s16x4*)&Bh[eb] = *(s16x4*)hv;
        *(s16x4*)&Bl[eb] = *(s16x4*)lv;
      }
      __syncthreads();
      // ---- compute: 24 MFMAs / wave / k-tile ----
      const int fo = ((lane >> 4) << 7) + (mrow << 3);
      s16x8 ah[2], al[2];
#pragma unroll
      for (int g = 0; g < 2; g++) {
        int ab = ((wm * 2 + g) << 9) + fo;
        ah[g] = *(const s16x8*)&Ah[ab];
        al[g] = *(const s16x8*)&Al[ab];
      }
#pragma unroll
      for (int j = 0; j < 4; j++) {
        int bb = ((wn * 4 + j) << 9) + fo;
        s16x8 bhj = *(const s16x8*)&Bh[bb];
        s16x8 blj = *(const s16x8*)&Bl[bb];
#pragma unroll
        for (int g = 0; g < 2; g++) {
          acc[g][j] = __builtin_amdgcn_mfma_f32_16x16x32_bf16(ah[g], bhj, acc[g][j], 0, 0, 0);
          acc[g][j] = __builtin_amdgcn_mfma_f32_16x16x32_bf16(al[g], bhj, acc[g][j], 0, 0, 0);
          acc[g][j] = __builtin_amdgcn_mfma_f32_16x16x32_bf16(ah[g], blj, acc[g][j], 0, 0, 0);
        }
      }
      __syncthreads();
    }
    // ---- epilogue for this col tile: C write (+ optional fused logits) ----
    float asv[4], adv[4];
    if (a_s) {
#pragma unroll
      for (int j = 0; j < 4; j++) {
        int c = bn + wn * 64 + j * 16 + mrow;
        asv[j] = a_s[c];
        adv[j] = a_d[c];
      }
    }
    const int head = bn >> lshift;
#pragma unroll
    for (int g = 0; g < 2; g++) {
#pragma unroll
      for (int r = 0; r < 4; r++) {
        int row = bm + wm * 32 + g * 16 + rq + r;
        bool rok = row < M;
        float ps = 0.f, pd = 0.f;
#pragma unroll
        for (int j = 0; j < 4; j++) {
          int ccol = bn + wn * 64 + j * 16 + mrow;
          float v = acc[g][j][r];
          if (rok) C[(size_t)row * ldC + col0 + ccol] = v;
          ps += v * asv[j];
          pd += v * adv[j];
        }
        if (a_s) {
#pragma unroll
          for (int off = 1; off < 16; off <<= 1) {
            ps += __shfl_xor(ps, off);
            pd += __shfl_xor(pd, off);
          }
          if (mrow == 0 && rok) {
            atomAddF(&als[(size_t)head * N_NODES + row], ps);
            atomAddF(&ald[(size_t)head * N_NODES + row], pd);
          }
        }
      }
    }
  }
}

// -------- small fp32 GEMM (FC head only) --------
__global__ __launch_bounds__(256) void k_gemm(
    const float* __restrict__ A, const float* __restrict__ W,
    const float* __restrict__ bias, float* __restrict__ C,
    int M, int K, int Nsub, int ldW, int ldC, int col0, int flags) {
  __shared__ float As[16][68];
  __shared__ float Bs[16][68];
  const int bm = blockIdx.y * 64;
  const int bn = blockIdx.x * 64;
  const int tid = threadIdx.x;
  const int tm = (tid >> 4) << 2;
  const int tn = (tid & 15) << 2;
  float acc[4][4] = {};
  for (int k0 = 0; k0 < K; k0 += 16) {
    {
      int idx = tid * 4;
      int row = idx >> 4;
      int kk = idx & 15;
      const float* ap = A + (size_t)(bm + row) * K + k0 + kk;
      bool rok = (bm + row) < M;
#pragma unroll
      for (int i = 0; i < 4; i++) {
        int kcur = k0 + kk + i;
        As[kk + i][row] = (rok && kcur < K) ? ap[i] : 0.f;
      }
    }
#pragma unroll
    for (int i = 0; i < 4; i++) {
      int idx = tid + i * 256;
      int kk = idx >> 6;
      int nn = idx & 63;
      int kcur = k0 + kk;
      Bs[kk][nn] = (kcur < K && (bn + nn) < Nsub)
                       ? W[(size_t)kcur * ldW + col0 + bn + nn] : 0.f;
    }
    __syncthreads();
#pragma unroll
    for (int kk = 0; kk < 16; kk++) {
      float av[4], bv[4];
#pragma unroll
      for (int i = 0; i < 4; i++) av[i] = As[kk][tm + i];
#pragma unroll
      for (int j = 0; j < 4; j++) bv[j] = Bs[kk][tn + j];
#pragma unroll
      for (int i = 0; i < 4; i++)
#pragma unroll
        for (int j = 0; j < 4; j++) acc[i][j] += av[i] * bv[j];
    }
    __syncthreads();
  }
#pragma unroll
  for (int i = 0; i < 4; i++) {
    int row = bm + tm + i;
    if (row >= M) continue;
#pragma unroll
    for (int j = 0; j < 4; j++) {
      int col = bn + tn + j;
      if (col >= Nsub) continue;
      float v = acc[i][j];
      if (flags & 1) v += bias[col0 + col];
      if (flags & 2) v = fmaxf(v, 0.f);
      C[(size_t)row * ldC + col] = v;
    }
  }
}

// ---------------- fused GCN aggregation + ReLU + BN -> packed out (unroll-2) ----------------
template <int VPT>
__global__ __launch_bounds__(256) void k_gcn_fused(
    const float* __restrict__ h, const float* __restrict__ dinv,
    const int* __restrict__ rowptr, const int* __restrict__ csr_src,
    const float* __restrict__ bias, const float* __restrict__ g,
    const float* __restrict__ b, const float* __restrict__ m,
    const float* __restrict__ vv, unsigned* __restrict__ out, int n, int F) {
  using V = typename VecT<VPT>::type;
  using UV = typename UVecT<VPT>::type;
  int wid = (blockIdx.x * blockDim.x + threadIdx.x) >> 6;
  int lane = threadIdx.x & 63;
  if (wid >= n) return;
  const int fo = lane * VPT;
  float dd = dinv[wid];
  V acc0 = *(const V*)(h + (size_t)wid * F + fo) * (dd * dd) + *(const V*)(bias + fo);
  V acc1 = {};
  int e0 = rowptr[wid], e1 = rowptr[wid + 1];
  int e = e0;
  for (; e + 1 < e1; e += 2) {
    int s0 = csr_src[e], s1 = csr_src[e + 1];
    float w0 = dinv[s0] * dd, w1 = dinv[s1] * dd;
    acc0 += *(const V*)(h + (size_t)s0 * F + fo) * w0;
    acc1 += *(const V*)(h + (size_t)s1 * F + fo) * w1;
  }
  if (e < e1) {
    int s0 = csr_src[e];
    acc0 += *(const V*)(h + (size_t)s0 * F + fo) * (dinv[s0] * dd);
  }
  acc0 += acc1;
  V mg = *(const V*)(m + fo);
  V vg = *(const V*)(vv + fo);
  V gg = *(const V*)(g + fo);
  V bg = *(const V*)(b + fo);
  UV res;
#pragma unroll
  for (int u = 0; u < VPT; u++) {
    float val = fmaxf(acc0[u], 0.f);
    res[u] = packsplit((val - mg[u]) * rsqrtf(vg[u] + BN_EPS) * gg[u] + bg[u]);
  }
  *(UV*)(out + (size_t)wid * F + fo) = res;
}

// ---------------- fused single-head GAT (GAT1, C=256) unroll-2 ----------------
template <int VPT>
__global__ __launch_bounds__(256) void k_gat_fused(
    const float* __restrict__ h, int ldH,
    const float* __restrict__ als, const float* __restrict__ ald,
    const int* __restrict__ rowptr, const int* __restrict__ csr_src,
    const float* __restrict__ bias, const float* __restrict__ g,
    const float* __restrict__ b, const float* __restrict__ m,
    const float* __restrict__ vv, unsigned* __restrict__ out, int ldO, int col0, int n) {
  using V = typename VecT<VPT>::type;
  using UV = typename UVecT<VPT>::type;
  int wid = (blockIdx.x * blockDim.x + threadIdx.x) >> 6;
  int lane = threadIdx.x & 63;
  if (wid >= n) return;
  const int co = lane * VPT;
  float aldd = ald[wid];
  float self_lg = lrelu(als[wid] + aldd);
  int e0 = rowptr[wid], e1 = rowptr[wid + 1];
  float mx = self_lg;
  for (int e = e0; e < e1; e++) mx = fmaxf(mx, lrelu(als[csr_src[e]] + aldd));
  float den = __expf(self_lg - mx);
  V acc0 = *(const V*)(h + (size_t)wid * ldH + co) * den;
  V acc1 = {};
  float den1 = 0.f;
  int e = e0;
  for (; e + 1 < e1; e += 2) {
    int s0 = csr_src[e], s1 = csr_src[e + 1];
    float w0 = __expf(lrelu(als[s0] + aldd) - mx);
    float w1 = __expf(lrelu(als[s1] + aldd) - mx);
    den += w0; den1 += w1;
    acc0 += *(const V*)(h + (size_t)s0 * ldH + co) * w0;
    acc1 += *(const V*)(h + (size_t)s1 * ldH + co) * w1;
  }
  if (e < e1) {
    int s0 = csr_src[e];
    float w0 = __expf(lrelu(als[s0] + aldd) - mx);
    den += w0;
    acc0 += *(const V*)(h + (size_t)s0 * ldH + co) * w0;
  }
  acc0 += acc1;
  den += den1;
  float rden = 1.f / den;
  const int fo = col0 + co;
  V bi = *(const V*)(bias + fo);
  V mg = *(const V*)(m + fo);
  V vg = *(const V*)(vv + fo);
  V gg = *(const V*)(g + fo);
  V bg = *(const V*)(b + fo);
  UV res;
#pragma unroll
  for (int u = 0; u < VPT; u++) {
    float val = fmaxf(acc0[u] * rden + bi[u], 0.f);
    res[u] = packsplit((val - mg[u]) * rsqrtf(vg[u] + BN_EPS) * gg[u] + bg[u]);
  }
  *(UV*)(out + (size_t)wid * ldO + fo) = res;
}

// ---------------- merged 3-head GAT agg (GAT2/3: C=128, HC=384) ----------------
__global__ __launch_bounds__(256) void k_gat_fused3(
    const float* __restrict__ h,              // [n, 384] fp32
    const float* __restrict__ als3, const float* __restrict__ ald3,  // [3, n]
    const int* __restrict__ rowptr, const int* __restrict__ csr_src,
    const float* __restrict__ bias, const float* __restrict__ g,
    const float* __restrict__ b, const float* __restrict__ m,
    const float* __restrict__ vv, unsigned* __restrict__ out, int n) {
  int wid = (blockIdx.x * blockDim.x + threadIdx.x) >> 6;
  int lane = threadIdx.x & 63;
  if (wid >= n) return;
  const int co = lane * 2;
  float aldd[3], mx[3], den[3];
  f32x2 acc[3];
#pragma unroll
  for (int hh = 0; hh < 3; hh++) {
    aldd[hh] = ald3[(size_t)hh * N_NODES + wid];
    mx[hh] = lrelu(als3[(size_t)hh * N_NODES + wid] + aldd[hh]);  // self logit
  }
  int e0 = rowptr[wid], e1 = rowptr[wid + 1];
  for (int e = e0; e < e1; e++) {
    int s = csr_src[e];
#pragma unroll
    for (int hh = 0; hh < 3; hh++)
      mx[hh] = fmaxf(mx[hh], lrelu(als3[(size_t)hh * N_NODES + s] + aldd[hh]));
  }
#pragma unroll
  for (int hh = 0; hh < 3; hh++) {
    float ws = __expf(lrelu(als3[(size_t)hh * N_NODES + wid] + aldd[hh]) - mx[hh]);
    den[hh] = ws;
    acc[hh] = *(const f32x2*)(h + (size_t)wid * 384 + hh * 128 + co) * ws;
  }
  for (int e = e0; e < e1; e++) {
    int s = csr_src[e];
    const float* hs = h + (size_t)s * 384 + co;
#pragma unroll
    for (int hh = 0; hh < 3; hh++) {
      float w = __expf(lrelu(als3[(size_t)hh * N_NODES + s] + aldd[hh]) - mx[hh]);
      den[hh] += w;
      acc[hh] += *(const f32x2*)(hs + hh * 128) * w;
    }
  }
#pragma unroll
  for (int hh = 0; hh < 3; hh++) {
    float rden = 1.f / den[hh];
    int fo = hh * 128 + co;
    u32x2 res;
#pragma unroll
    for (int u = 0; u < 2; u++) {
      float val = fmaxf(acc[hh][u] * rden + bias[fo + u], 0.f);
      res[u] = packsplit((val - m[fo + u]) * rsqrtf(vv[fo + u] + BN_EPS) * g[fo + u] + b[fo + u]);
    }
    *(u32x2*)(out + (size_t)wid * 384 + fo) = res;
  }
}

// ---------------- pooling (packed input) & final FC ----------------
__global__ void k_pool_add(float* __restrict__ pooled, const unsigned* __restrict__ act,
                           const int* __restrict__ batch, int n, int F, int off) {
  long long idx = (long long)blockIdx.x * blockDim.x + threadIdx.x;
  if (idx >= (long long)n * F) return;
  int node = (int)(idx / F);
  int f = (int)(idx % F);
  atomAddF(&pooled[(size_t)batch[node] * 512 + off + f], unpackf(act[idx]));
}
__global__ void k_fc3(const float* __restrict__ in, const float* __restrict__ w,
                      const float* __restrict__ b, float* __restrict__ out, int g) {
  int wid = (blockIdx.x * blockDim.x + threadIdx.x) >> 6;
  int lane = threadIdx.x & 63;
  if (wid >= g) return;
  float v = in[wid * 64 + lane] * w[lane];
#pragma unroll
  for (int off = 32; off > 0; off >>= 1) v += __shfl_down(v, off);
  if (lane == 0) out[wid] = fmaxf(v + b[0], 0.f);
}

// ---------------- host side ----------------
static void gemm_fp32(hipStream_t s, const float* A, const float* W, const float* bias,
                      float* C, int M, int K, int Nsub, int ldW, int ldC, int col0, int flags) {
  dim3 grid(cdiv(Nsub, 64), cdiv(M, 64));
  k_gemm<<<grid, 256, 0, s>>>(A, W, bias, C, M, K, Nsub, ldW, ldC, col0, flags);
}

static void gemm_mfma(hipStream_t s, const void* A, int lda, int amode,
                      const float* W, int ldW, int wcol0, int K, int Kpad,
                      unsigned* Wt, float* C, int M, int Nsub, int ldC, int ccol0,
                      const float* a_s = nullptr, const float* a_d = nullptr,
                      float* als = nullptr, float* ald = nullptr, int lshift = 30) {
  dim3 wg(cdiv(Nsub, 256), Kpad);
  k_buildwt<<<wg, 256, 0, s>>>(W, ldW, wcol0, Nsub, K, Kpad, Wt);
  dim3 grid(cdiv(M, 64));
  k_mfma_gemm<<<grid, 256, 0, s>>>((const float*)A, lda, amode, K, Wt, Kpad, Nsub / 128,
                                   C, M, ldC, ccol0, a_s, a_d, als, ald, lshift);
}

extern "C" void kernel_launch(void* const* d_in, const int* in_sizes, int n_in,
                              void* d_out, int out_size, void* d_ws, size_t ws_size,
                              hipStream_t stream) {
  const float* x = (const float*)d_in[0];
  const int* ei = (const int*)d_in[1];
  const int* batch = (const int*)d_in[2];
  const float* gw1 = (const float*)d_in[3];  const float* gb1 = (const float*)d_in[4];
  const float* gw2 = (const float*)d_in[5];  const float* gb2 = (const float*)d_in[6];
  const float* gw3 = (const float*)d_in[7];  const float* gb3 = (const float*)d_in[8];
  const float* g01g = (const float*)d_in[9];  const float* g01b = (const float*)d_in[10];
  const float* g01m = (const float*)d_in[11]; const float* g01v = (const float*)d_in[12];
  const float* g02g = (const float*)d_in[13]; const float* g02b = (const float*)d_in[14];
  const float* g02m = (const float*)d_in[15]; const float* g02v = (const float*)d_in[16];
  const float* g03g = (const float*)d_in[17]; const float* g03b = (const float*)d_in[18];
  const float* g03m = (const float*)d_in[19]; const float* g03v = (const float*)d_in[20];
  const float* g11g = (const float*)d_in[21]; const float* g11b = (const float*)d_in[22];
  const float* g11m = (const float*)d_in[23]; const float* g11v = (const float*)d_in[24];
  const float* g12g = (const float*)d_in[25]; const float* g12b = (const float*)d_in[26];
  const float* g12m = (const float*)d_in[27]; const float* g12v = (const float*)d_in[28];
  const float* g13g = (const float*)d_in[29]; const float* g13b = (const float*)d_in[30];
  const float* g13m = (const float*)d_in[31]; const float* g13v = (const float*)d_in[32];
  const float* aw1 = (const float*)d_in[33]; const float* as1 = (const float*)d_in[34];
  const float* ad1 = (const float*)d_in[35]; const float* ab1 = (const float*)d_in[36];
  const float* aw2 = (const float*)d_in[37]; const float* as2 = (const float*)d_in[38];
  const float* ad2 = (const float*)d_in[39]; const float* ab2 = (const float*)d_in[40];
  const float* aw3 = (const float*)d_in[41]; const float* as3 = (const float*)d_in[42];
  const float* ad3 = (const float*)d_in[43]; const float* ab3 = (const float*)d_in[44];
  const float* f1w = (const float*)d_in[45]; const float* f1b = (const float*)d_in[46];
  const float* f2w = (const float*)d_in[47]; const float* f2b = (const float*)d_in[48];
  const float* f3w = (const float*)d_in[49]; const float* f3b = (const float*)d_in[50];

  const int* src = ei;
  const int* dst = ei + N_EDGES;

  // ---- workspace carve: exactly round-2's proven 239.456 MB ----
  size_t need = 0;
  need += (size_t)N_NODES * 768;   // OUTP (packed-split activations)
  need += (size_t)N_NODES * 384;   // H (fp32 GEMM out)
  need += (size_t)N_NODES;         // dinv
  need += (size_t)N_NODES * 6;     // als3 + ald3 (head-major; degi/cursor alias)
  need += (size_t)N_NODES + 1;     // rowptr
  need += (size_t)N_EDGES;         // csr_src
  need += (size_t)N_GRAPHS * (512 + 256 + 64);  // pooled + fc1/fc2 (Wt aliases fc)
  if (ws_size < need * sizeof(float)) return;  // clean-fail guard

  float* wp = (float*)d_ws;
  unsigned* OUTP = (unsigned*)wp; wp += (size_t)N_NODES * 768;
  float* H = wp;       wp += (size_t)N_NODES * 384;
  float* dinv = wp;    wp += N_NODES;
  float* als3 = wp;    wp += (size_t)N_NODES * 3;
  float* ald3 = wp;    wp += (size_t)N_NODES * 3;
  int* rowptr = (int*)wp;  wp += N_NODES + 1;
  int* csr_src = (int*)wp; wp += N_EDGES;
  float* pooled = wp; wp += (size_t)N_GRAPHS * 512;
  float* fc1 = wp;    wp += (size_t)N_GRAPHS * 256;
  float* fc2 = wp;    wp += (size_t)N_GRAPHS * 64;
  int* degi = (int*)als3;
  int* cursor = (int*)ald3;
  unsigned* Wt = (unsigned*)fc1;  // 294912 u32 max, aliases fc1/fc2 (640000 words)

  // ---- CSR build (once) ----
  k_zero_i<<<cdiv(N_NODES, 256), 256, 0, stream>>>(degi, N_NODES);
  k_deg<<<cdiv(N_EDGES, 256), 256, 0, stream>>>(degi, dst, N_EDGES);
  k_dinv<<<cdiv(N_NODES, 256), 256, 0, stream>>>(degi, dinv, N_NODES);
  k_scan<<<1, 1024, 0, stream>>>(degi, rowptr, cursor, N_NODES);
  k_csr_scatter<<<cdiv(N_EDGES, 256), 256, 0, stream>>>(src, dst, rowptr, cursor, csr_src, N_EDGES);
  k_zero<<<cdiv((long long)N_GRAPHS * 512, 256), 256, 0, stream>>>(pooled, (long long)N_GRAPHS * 512);

  const int nodeWaveGrid = cdiv((long long)N_NODES * 64, 256);

  // ---- GCN path ----
  struct { const float *w, *bias, *g, *b, *m, *v; int F; } gcn[3] = {
    {gw1, gb1, g01g, g01b, g01m, g01v, 256},
    {gw2, gb2, g02g, g02b, g02m, g02v, 128},
    {gw3, gb3, g03g, g03b, g03m, g03v, 128}};
  int gF = F_IN;
  for (int l = 0; l < 3; l++) {
    int F = gcn[l].F;
    if (l == 0)
      gemm_mfma(stream, x, F_IN, 0, gcn[l].w, F, 0, F_IN, 384, Wt, H, N_NODES, F, F, 0);
    else
      gemm_mfma(stream, OUTP, gF, 1, gcn[l].w, F, 0, gF, gF, Wt, H, N_NODES, F, F, 0);
    if (F == 256)
      k_gcn_fused<4><<<nodeWaveGrid, 256, 0, stream>>>(H, dinv, rowptr, csr_src,
          gcn[l].bias, gcn[l].g, gcn[l].b, gcn[l].m, gcn[l].v, OUTP, N_NODES, F);
    else
      k_gcn_fused<2><<<nodeWaveGrid, 256, 0, stream>>>(H, dinv, rowptr, csr_src,
          gcn[l].bias, gcn[l].g, gcn[l].b, gcn[l].m, gcn[l].v, OUTP, N_NODES, F);
    gF = F;
  }
  k_pool_add<<<cdiv((long long)N_NODES * 128, 256), 256, 0, stream>>>(pooled, OUTP, batch, N_NODES, 128, 0);

  // ---- GAT1: input x, C=256, per-head GEMM (logits fused) + fused agg ----
  {
    int C = 256, HC = 768;
    for (int hh = 0; hh < 3; hh++) {
      k_zero<<<cdiv((long long)N_NODES * 6, 256), 256, 0, stream>>>(als3, (long long)N_NODES * 6);
      gemm_mfma(stream, x, F_IN, 0, aw1, HC, hh * C, F_IN, 384, Wt, H, N_NODES, C, C, 0,
                as1 + hh * C, ad1 + hh * C, als3, ald3, 30);
      k_gat_fused<4><<<nodeWaveGrid, 256, 0, stream>>>(H, C, als3, ald3, rowptr, csr_src,
          ab1, g11g, g11b, g11m, g11v, OUTP, HC, hh * C, N_NODES);
    }
  }

  // ---- GAT2 & GAT3: one GEMM (3-head logits fused), merged 3-head agg ----
  struct { const float *w, *s, *d, *bias, *g, *b, *m, *v; int K; } gat[2] = {
    {aw2, as2, ad2, ab2, g12g, g12b, g12m, g12v, 768},
    {aw3, as3, ad3, ab3, g13g, g13b, g13m, g13v, 384}};
  for (int l = 0; l < 2; l++) {
    k_zero<<<cdiv((long long)N_NODES * 6, 256), 256, 0, stream>>>(als3, (long long)N_NODES * 6);
    gemm_mfma(stream, OUTP, gat[l].K, 1, gat[l].w, 384, 0, gat[l].K, gat[l].K, Wt, H, N_NODES, 384, 384, 0,
              gat[l].s, gat[l].d, als3, ald3, 7);
    k_gat_fused3<<<nodeWaveGrid, 256, 0, stream>>>(H, als3, ald3, rowptr, csr_src,
        gat[l].bias, gat[l].g, gat[l].b, gat[l].m, gat[l].v, OUTP, N_NODES);
  }
  k_pool_add<<<cdiv((long long)N_NODES * 384, 256), 256, 0, stream>>>(pooled, OUTP, batch, N_NODES, 384, 128);

  // ---- FC head ----
  gemm_fp32(stream, pooled, f1w, f1b, fc1, N_GRAPHS, 512, 256, 256, 256, 0, 3);
  gemm_fp32(stream, fc1, f2w, f2b, fc2, N_GRAPHS, 256, 64, 64, 64, 0, 3);
  k_fc3<<<cdiv((long long)N_GRAPHS * 64, 256), 256, 0, stream>>>(fc2, f3w, f3b, (float*)d_out, N_GRAPHS);
}

// Round 10
// 1451.503 us; speedup vs baseline: 1.5135x; 1.5135x over previous
//
#include <hip/hip_runtime.h>
#include <cstdint>
#include <cstddef>

#define N_NODES 50000
#define N_EDGES 200000
#define N_GRAPHS 2000
#define F_IN 373
#define NEG_SLOPE 0.2f
#define BN_EPS 1e-5f

typedef float f32x4 __attribute__((ext_vector_type(4)));
typedef float f32x2 __attribute__((ext_vector_type(2)));
typedef short s16x8 __attribute__((ext_vector_type(8)));
typedef short s16x4 __attribute__((ext_vector_type(4)));
typedef unsigned int u32x4 __attribute__((ext_vector_type(4)));
typedef unsigned int u32x2 __attribute__((ext_vector_type(2)));

template <int VPT> struct VecT;
template <> struct VecT<2> { using type = f32x2; };
template <> struct VecT<4> { using type = f32x4; };
template <int VPT> struct UVecT;
template <> struct UVecT<2> { using type = u32x2; };
template <> struct UVecT<4> { using type = u32x4; };

static inline int cdiv(long long a, long long b) { return (int)((a + b - 1) / b); }

__device__ __forceinline__ float lrelu(float x) { return x > 0.f ? x : NEG_SLOPE * x; }

__device__ __forceinline__ void atomAddF(float* p, float v) {
#if defined(__HIP_DEVICE_COMPILE__)
  unsafeAtomicAdd(p, v);
#else
  atomicAdd(p, v);
#endif
}

__device__ __forceinline__ unsigned short bf16rne(float f) {
  unsigned u = __float_as_uint(f);
  unsigned r = u + 0x7fffu + ((u >> 16) & 1u);
  return (unsigned short)(r >> 16);
}
__device__ __forceinline__ void split2(float f, unsigned short& hi, unsigned short& lo) {
  hi = bf16rne(f);
  float fh = __uint_as_float(((unsigned)hi) << 16);
  lo = bf16rne(f - fh);
}
__device__ __forceinline__ unsigned packsplit(float f) {
  unsigned short hi, lo;
  split2(f, hi, lo);
  return (((unsigned)hi) << 16) | (unsigned)lo;
}
__device__ __forceinline__ float unpackf(unsigned w) {
  return __uint_as_float(w & 0xffff0000u) + __uint_as_float(w << 16);
}

// fragment-order LDS layout (shorts) within a row-block:
// elem(row,k) -> (row>>4)*512 + (k>>3)*128 + (row&15)*8 + (k&7)
__device__ __forceinline__ int ebase(int row, int k) {
  return ((row >> 4) << 9) + ((k >> 3) << 7) + ((row & 15) << 3) + (k & 7);
}

// HBM -> LDS direct DMA, 16B per lane (lds dest = base + lane*16, wave-uniform base)
typedef __attribute__((address_space(3))) unsigned short lds_us;
typedef __attribute__((address_space(1))) const unsigned short glb_us;
__device__ __forceinline__ void dma16(const unsigned short* g, unsigned short* l) {
  __builtin_amdgcn_global_load_lds((glb_us*)g, (lds_us*)l, 16, 0, 0);
}

// ---------------- utility ----------------
__global__ void k_zero(float* p, long long n) {
  long long i = (long long)blockIdx.x * blockDim.x + threadIdx.x;
  if (i < n) p[i] = 0.f;
}
__global__ void k_zero_i(int* p, int n) {
  int i = blockIdx.x * blockDim.x + threadIdx.x;
  if (i < n) p[i] = 0;
}
__global__ void k_deg(int* __restrict__ deg, const int* __restrict__ dst, int e) {
  int i = blockIdx.x * blockDim.x + threadIdx.x;
  if (i < e) atomicAdd(&deg[dst[i]], 1);
}
__global__ void k_dinv(const int* __restrict__ deg, float* __restrict__ dinv, int n) {
  int i = blockIdx.x * blockDim.x + threadIdx.x;
  if (i < n) dinv[i] = rsqrtf((float)deg[i] + 1.0f);
}

__global__ void k_scan(const int* __restrict__ deg, int* __restrict__ rowptr,
                       int* __restrict__ cursor, int n) {
  __shared__ int wsum[16];
  __shared__ int carry_s;
  const int lane = threadIdx.x & 63;
  const int wid = threadIdx.x >> 6;
  if (threadIdx.x == 0) carry_s = 0;
  __syncthreads();
  for (int base = 0; base < n; base += 1024) {
    int i = base + threadIdx.x;
    int v = (i < n) ? deg[i] : 0;
    int s = v;
#pragma unroll
    for (int off = 1; off < 64; off <<= 1) {
      int t = __shfl_up(s, off);
      if (lane >= off) s += t;
    }
    if (lane == 63) wsum[wid] = s;
    __syncthreads();
    if (threadIdx.x == 0) {
      int acc = carry_s;
#pragma unroll
      for (int w = 0; w < 16; w++) { int t = wsum[w]; wsum[w] = acc; acc += t; }
      carry_s = acc;
    }
    __syncthreads();
    if (i < n) { rowptr[i] = wsum[wid] + s - v; cursor[i] = 0; }
    __syncthreads();
  }
  if (threadIdx.x == 0) rowptr[n] = carry_s;
}

__global__ void k_csr_scatter(const int* __restrict__ src, const int* __restrict__ dst,
                              const int* __restrict__ rowptr, int* __restrict__ cursor,
                              int* __restrict__ csr_src, int e) {
  int i = blockIdx.x * blockDim.x + threadIdx.x;
  if (i >= e) return;
  int d = dst[i];
  int pos = rowptr[d] + atomicAdd(&cursor[d], 1);
  csr_src[pos] = src[i];
}

// build Wt hi/lo bf16 planes in DMA-ready tile-fragment order:
// plane[((n>>7)*(Kpad>>5) + (k>>5))*4096 + frag(n&127, k&31)]
__global__ void k_buildwt2(const float* __restrict__ W, int ldW, int col0, int Nsub,
                           int K, int Kpad, unsigned short* __restrict__ WtH,
                           unsigned short* __restrict__ WtL) {
  int n = blockIdx.x * blockDim.x + threadIdx.x;
  int k = blockIdx.y;
  if (n >= Nsub) return;
  float v = (k < K) ? W[(size_t)k * ldW + col0 + n] : 0.f;
  unsigned short hi, lo;
  split2(v, hi, lo);
  size_t off = ((size_t)(n >> 7) * (Kpad >> 5) + (k >> 5)) * 4096
             + ((((n >> 4) & 7)) << 9) + (((k >> 3) & 3) << 7) + ((n & 15) << 3) + (k & 7);
  WtH[off] = hi;
  WtL[off] = lo;
}

// ---------------- MFMA split-bf16 GEMM: 64x128 tile, 2-D grid, B via DMA ----------------
// C[M, Nsub] (ld=ldC, col offset col0) = A[M, K] @ Wt^T  (WtH/WtL tiled planes)
// amode: 0 = fp32 scalar w/ k<Kact guard; 1 = packed u32 float4; 2 = fp32 float4.
// a_s != null: fuse attention logits (als/ald head-major, head = bn >> lshift).
__global__ __launch_bounds__(256) void k_mfma_gemm(
    const float* __restrict__ Ap, int lda, int amode, int Kact,
    const unsigned short* __restrict__ WtH, const unsigned short* __restrict__ WtL,
    int Kpad,
    float* __restrict__ C, int M, int ldC, int col0,
    const float* __restrict__ a_s, const float* __restrict__ a_d,
    float* __restrict__ als, float* __restrict__ ald, int lshift) {
  __shared__ unsigned short Ah[64 * 32], Al[64 * 32];     // 4 KB each
  __shared__ unsigned short Bh[128 * 32], Bl[128 * 32];   // 8 KB each (DMA targets)
  const int bm = blockIdx.y * 64;
  const int bn = blockIdx.x * 128;
  const int tid = threadIdx.x;
  const int lane = tid & 63;
  const int wave = tid >> 6;
  const int wm = wave & 1;   // row half (32 rows)
  const int wn = wave >> 1;  // col half (64 cols)

  f32x4 acc[2][4];
#pragma unroll
  for (int i = 0; i < 2; i++)
#pragma unroll
    for (int j = 0; j < 4; j++) acc[i][j] = (f32x4){0.f, 0.f, 0.f, 0.f};

  const int srow = tid >> 3;        // 0..31
  const int skq = (tid & 7) << 2;   // 0,4,...,28
  const int mrow = lane & 15;
  const int rq = (lane >> 4) << 2;
  const int ktiles = Kpad >> 5;
  const size_t btile0 = (size_t)(bn >> 7) * ktiles * 4096;

  for (int k0 = 0; k0 < Kpad; k0 += 32) {
    // ---- stage B: direct HBM->LDS DMA, tile-fragment order, 2+2 insts/wave ----
    {
      const unsigned short* srcH = WtH + btile0 + (size_t)(k0 >> 5) * 4096;
      const unsigned short* srcL = WtL + btile0 + (size_t)(k0 >> 5) * 4096;
#pragma unroll
      for (int i = 0; i < 2; i++) {
        int c = wave * 2 + i;              // chunk 0..7 (1 KB each)
        dma16(srcH + c * 512 + lane * 8, &Bh[c * 512]);
        dma16(srcL + c * 512 + lane * 8, &Bl[c * 512]);
      }
    }
    // ---- stage A: 64 rows via VGPR path ----
#pragma unroll
    for (int i = 0; i < 2; i++) {
      int row = i * 32 + srow;
      int grow = bm + row;
      unsigned short hv[4], lv[4];
      if (amode == 1) {
        u32x4 v = (grow < M) ? *(const u32x4*)((const unsigned*)Ap + (size_t)grow * lda + k0 + skq)
                             : (u32x4){0u, 0u, 0u, 0u};
#pragma unroll
        for (int u = 0; u < 4; u++) { hv[u] = (unsigned short)(v[u] >> 16); lv[u] = (unsigned short)(v[u] & 0xffffu); }
      } else if (amode == 2) {
        f32x4 v = (grow < M) ? *(const f32x4*)(Ap + (size_t)grow * lda + k0 + skq)
                             : (f32x4){0.f, 0.f, 0.f, 0.f};
#pragma unroll
        for (int u = 0; u < 4; u++) split2(v[u], hv[u], lv[u]);
      } else {
        const float* ap = Ap + (size_t)grow * lda;
#pragma unroll
        for (int u = 0; u < 4; u++) {
          int kc = k0 + skq + u;
          float f = (grow < M && kc < Kact) ? ap[kc] : 0.f;
          split2(f, hv[u], lv[u]);
        }
      }
      int eb = ebase(row, skq);
      *(s16x4*)&Ah[eb] = *(s16x4*)hv;
      *(s16x4*)&Al[eb] = *(s16x4*)lv;
    }
    __syncthreads();   // drains vmcnt (DMA) + lgkmcnt (LDS writes)
    // ---- compute: 24 MFMAs / wave / k-tile ----
    const int fo = ((lane >> 4) << 7) + (mrow << 3);
    s16x8 ah[2], al[2];
#pragma unroll
    for (int g = 0; g < 2; g++) {
      int ab = ((wm * 2 + g) << 9) + fo;
      ah[g] = *(const s16x8*)&Ah[ab];
      al[g] = *(const s16x8*)&Al[ab];
    }
#pragma unroll
    for (int j = 0; j < 4; j++) {
      int bb = ((wn * 4 + j) << 9) + fo;
      s16x8 bhj = *(const s16x8*)&Bh[bb];
      s16x8 blj = *(const s16x8*)&Bl[bb];
#pragma unroll
      for (int g = 0; g < 2; g++) {
        acc[g][j] = __builtin_amdgcn_mfma_f32_16x16x32_bf16(ah[g], bhj, acc[g][j], 0, 0, 0);
        acc[g][j] = __builtin_amdgcn_mfma_f32_16x16x32_bf16(al[g], bhj, acc[g][j], 0, 0, 0);
        acc[g][j] = __builtin_amdgcn_mfma_f32_16x16x32_bf16(ah[g], blj, acc[g][j], 0, 0, 0);
      }
    }
    __syncthreads();
  }
  // ---- epilogue: C write (+ optional fused logits) ----
  float asv[4], adv[4];
  if (a_s) {
#pragma unroll
    for (int j = 0; j < 4; j++) {
      int c = bn + wn * 64 + j * 16 + mrow;
      asv[j] = a_s[c];
      adv[j] = a_d[c];
    }
  }
  const int head = bn >> lshift;
#pragma unroll
  for (int g = 0; g < 2; g++) {
#pragma unroll
    for (int r = 0; r < 4; r++) {
      int row = bm + wm * 32 + g * 16 + rq + r;
      bool rok = row < M;
      float ps = 0.f, pd = 0.f;
#pragma unroll
      for (int j = 0; j < 4; j++) {
        int ccol = bn + wn * 64 + j * 16 + mrow;
        float v = acc[g][j][r];
        if (rok) C[(size_t)row * ldC + col0 + ccol] = v;
        ps += v * asv[j];
        pd += v * adv[j];
      }
      if (a_s) {
#pragma unroll
        for (int off = 1; off < 16; off <<= 1) {
          ps += __shfl_xor(ps, off);
          pd += __shfl_xor(pd, off);
        }
        if (mrow == 0 && rok) {
          atomAddF(&als[(size_t)head * N_NODES + row], ps);
          atomAddF(&ald[(size_t)head * N_NODES + row], pd);
        }
      }
    }
  }
}

// -------- small fp32 GEMM (FC head only) --------
__global__ __launch_bounds__(256) void k_gemm(
    const float* __restrict__ A, const float* __restrict__ W,
    const float* __restrict__ bias, float* __restrict__ C,
    int M, int K, int Nsub, int ldW, int ldC, int col0, int flags) {
  __shared__ float As[16][68];
  __shared__ float Bs[16][68];
  const int bm = blockIdx.y * 64;
  const int bn = blockIdx.x * 64;
  const int tid = threadIdx.x;
  const int tm = (tid >> 4) << 2;
  const int tn = (tid & 15) << 2;
  float acc[4][4] = {};
  for (int k0 = 0; k0 < K; k0 += 16) {
    {
      int idx = tid * 4;
      int row = idx >> 4;
      int kk = idx & 15;
      const float* ap = A + (size_t)(bm + row) * K + k0 + kk;
      bool rok = (bm + row) < M;
#pragma unroll
      for (int i = 0; i < 4; i++) {
        int kcur = k0 + kk + i;
        As[kk + i][row] = (rok && kcur < K) ? ap[i] : 0.f;
      }
    }
#pragma unroll
    for (int i = 0; i < 4; i++) {
      int idx = tid + i * 256;
      int kk = idx >> 6;
      int nn = idx & 63;
      int kcur = k0 + kk;
      Bs[kk][nn] = (kcur < K && (bn + nn) < Nsub)
                       ? W[(size_t)kcur * ldW + col0 + bn + nn] : 0.f;
    }
    __syncthreads();
#pragma unroll
    for (int kk = 0; kk < 16; kk++) {
      float av[4], bv[4];
#pragma unroll
      for (int i = 0; i < 4; i++) av[i] = As[kk][tm + i];
#pragma unroll
      for (int j = 0; j < 4; j++) bv[j] = Bs[kk][tn + j];
#pragma unroll
      for (int i = 0; i < 4; i++)
#pragma unroll
        for (int j = 0; j < 4; j++) acc[i][j] += av[i] * bv[j];
    }
    __syncthreads();
  }
#pragma unroll
  for (int i = 0; i < 4; i++) {
    int row = bm + tm + i;
    if (row >= M) continue;
#pragma unroll
    for (int j = 0; j < 4; j++) {
      int col = bn + tn + j;
      if (col >= Nsub) continue;
      float v = acc[i][j];
      if (flags & 1) v += bias[col0 + col];
      if (flags & 2) v = fmaxf(v, 0.f);
      C[(size_t)row * ldC + col] = v;
    }
  }
}

// ---------------- fused GCN aggregation + ReLU + BN -> packed out (unroll-2) ----------------
template <int VPT>
__global__ __launch_bounds__(256) void k_gcn_fused(
    const float* __restrict__ h, const float* __restrict__ dinv,
    const int* __restrict__ rowptr, const int* __restrict__ csr_src,
    const float* __restrict__ bias, const float* __restrict__ g,
    const float* __restrict__ b, const float* __restrict__ m,
    const float* __restrict__ vv, unsigned* __restrict__ out, int n, int F) {
  using V = typename VecT<VPT>::type;
  using UV = typename UVecT<VPT>::type;
  int wid = (blockIdx.x * blockDim.x + threadIdx.x) >> 6;
  int lane = threadIdx.x & 63;
  if (wid >= n) return;
  const int fo = lane * VPT;
  float dd = dinv[wid];
  V acc0 = *(const V*)(h + (size_t)wid * F + fo) * (dd * dd) + *(const V*)(bias + fo);
  V acc1 = {};
  int e0 = rowptr[wid], e1 = rowptr[wid + 1];
  int e = e0;
  for (; e + 1 < e1; e += 2) {
    int s0 = csr_src[e], s1 = csr_src[e + 1];
    float w0 = dinv[s0] * dd, w1 = dinv[s1] * dd;
    acc0 += *(const V*)(h + (size_t)s0 * F + fo) * w0;
    acc1 += *(const V*)(h + (size_t)s1 * F + fo) * w1;
  }
  if (e < e1) {
    int s0 = csr_src[e];
    acc0 += *(const V*)(h + (size_t)s0 * F + fo) * (dinv[s0] * dd);
  }
  acc0 += acc1;
  V mg = *(const V*)(m + fo);
  V vg = *(const V*)(vv + fo);
  V gg = *(const V*)(g + fo);
  V bg = *(const V*)(b + fo);
  UV res;
#pragma unroll
  for (int u = 0; u < VPT; u++) {
    float val = fmaxf(acc0[u], 0.f);
    res[u] = packsplit((val - mg[u]) * rsqrtf(vg[u] + BN_EPS) * gg[u] + bg[u]);
  }
  *(UV*)(out + (size_t)wid * F + fo) = res;
}

// ---------------- fused single-head GAT (GAT1, C=256) unroll-2 ----------------
template <int VPT>
__global__ __launch_bounds__(256) void k_gat_fused(
    const float* __restrict__ h, int ldH,
    const float* __restrict__ als, const float* __restrict__ ald,
    const int* __restrict__ rowptr, const int* __restrict__ csr_src,
    const float* __restrict__ bias, const float* __restrict__ g,
    const float* __restrict__ b, const float* __restrict__ m,
    const float* __restrict__ vv, unsigned* __restrict__ out, int ldO, int col0, int n) {
  using V = typename VecT<VPT>::type;
  using UV = typename UVecT<VPT>::type;
  int wid = (blockIdx.x * blockDim.x + threadIdx.x) >> 6;
  int lane = threadIdx.x & 63;
  if (wid >= n) return;
  const int co = lane * VPT;
  float aldd = ald[wid];
  float self_lg = lrelu(als[wid] + aldd);
  int e0 = rowptr[wid], e1 = rowptr[wid + 1];
  float mx = self_lg;
  for (int e = e0; e < e1; e++) mx = fmaxf(mx, lrelu(als[csr_src[e]] + aldd));
  float den = __expf(self_lg - mx);
  V acc0 = *(const V*)(h + (size_t)wid * ldH + co) * den;
  V acc1 = {};
  float den1 = 0.f;
  int e = e0;
  for (; e + 1 < e1; e += 2) {
    int s0 = csr_src[e], s1 = csr_src[e + 1];
    float w0 = __expf(lrelu(als[s0] + aldd) - mx);
    float w1 = __expf(lrelu(als[s1] + aldd) - mx);
    den += w0; den1 += w1;
    acc0 += *(const V*)(h + (size_t)s0 * ldH + co) * w0;
    acc1 += *(const V*)(h + (size_t)s1 * ldH + co) * w1;
  }
  if (e < e1) {
    int s0 = csr_src[e];
    float w0 = __expf(lrelu(als[s0] + aldd) - mx);
    den += w0;
    acc0 += *(const V*)(h + (size_t)s0 * ldH + co) * w0;
  }
  acc0 += acc1;
  den += den1;
  float rden = 1.f / den;
  const int fo = col0 + co;
  V bi = *(const V*)(bias + fo);
  V mg = *(const V*)(m + fo);
  V vg = *(const V*)(vv + fo);
  V gg = *(const V*)(g + fo);
  V bg = *(const V*)(b + fo);
  UV res;
#pragma unroll
  for (int u = 0; u < VPT; u++) {
    float val = fmaxf(acc0[u] * rden + bi[u], 0.f);
    res[u] = packsplit((val - mg[u]) * rsqrtf(vg[u] + BN_EPS) * gg[u] + bg[u]);
  }
  *(UV*)(out + (size_t)wid * ldO + fo) = res;
}

// ---------------- merged 3-head GAT agg (GAT2/3: C=128, HC=384) ----------------
__global__ __launch_bounds__(256) void k_gat_fused3(
    const float* __restrict__ h,              // [n, 384] fp32
    const float* __restrict__ als3, const float* __restrict__ ald3,  // [3, n]
    const int* __restrict__ rowptr, const int* __restrict__ csr_src,
    const float* __restrict__ bias, const float* __restrict__ g,
    const float* __restrict__ b, const float* __restrict__ m,
    const float* __restrict__ vv, unsigned* __restrict__ out, int n) {
  int wid = (blockIdx.x * blockDim.x + threadIdx.x) >> 6;
  int lane = threadIdx.x & 63;
  if (wid >= n) return;
  const int co = lane * 2;
  float aldd[3], mx[3], den[3];
  f32x2 acc[3];
#pragma unroll
  for (int hh = 0; hh < 3; hh++) {
    aldd[hh] = ald3[(size_t)hh * N_NODES + wid];
    mx[hh] = lrelu(als3[(size_t)hh * N_NODES + wid] + aldd[hh]);  // self logit
  }
  int e0 = rowptr[wid], e1 = rowptr[wid + 1];
  for (int e = e0; e < e1; e++) {
    int s = csr_src[e];
#pragma unroll
    for (int hh = 0; hh < 3; hh++)
      mx[hh] = fmaxf(mx[hh], lrelu(als3[(size_t)hh * N_NODES + s] + aldd[hh]));
  }
#pragma unroll
  for (int hh = 0; hh < 3; hh++) {
    float ws = __expf(lrelu(als3[(size_t)hh * N_NODES + wid] + aldd[hh]) - mx[hh]);
    den[hh] = ws;
    acc[hh] = *(const f32x2*)(h + (size_t)wid * 384 + hh * 128 + co) * ws;
  }
  for (int e = e0; e < e1; e++) {
    int s = csr_src[e];
    const float* hs = h + (size_t)s * 384 + co;
#pragma unroll
    for (int hh = 0; hh < 3; hh++) {
      float w = __expf(lrelu(als3[(size_t)hh * N_NODES + s] + aldd[hh]) - mx[hh]);
      den[hh] += w;
      acc[hh] += *(const f32x2*)(hs + hh * 128) * w;
    }
  }
#pragma unroll
  for (int hh = 0; hh < 3; hh++) {
    float rden = 1.f / den[hh];
    int fo = hh * 128 + co;
    u32x2 res;
#pragma unroll
    for (int u = 0; u < 2; u++) {
      float val = fmaxf(acc[hh][u] * rden + bias[fo + u], 0.f);
      res[u] = packsplit((val - m[fo + u]) * rsqrtf(vv[fo + u] + BN_EPS) * g[fo + u] + b[fo + u]);
    }
    *(u32x2*)(out + (size_t)wid * 384 + fo) = res;
  }
}

// ---------------- pooling (packed input) & final FC ----------------
__global__ void k_pool_add(float* __restrict__ pooled, const unsigned* __restrict__ act,
                           const int* __restrict__ batch, int n, int F, int off) {
  long long idx = (long long)blockIdx.x * blockDim.x + threadIdx.x;
  if (idx >= (long long)n * F) return;
  int node = (int)(idx / F);
  int f = (int)(idx % F);
  atomAddF(&pooled[(size_t)batch[node] * 512 + off + f], unpackf(act[idx]));
}
__global__ void k_fc3(const float* __restrict__ in, const float* __restrict__ w,
                      const float* __restrict__ b, float* __restrict__ out, int g) {
  int wid = (blockIdx.x * blockDim.x + threadIdx.x) >> 6;
  int lane = threadIdx.x & 63;
  if (wid >= g) return;
  float v = in[wid * 64 + lane] * w[lane];
#pragma unroll
  for (int off = 32; off > 0; off >>= 1) v += __shfl_down(v, off);
  if (lane == 0) out[wid] = fmaxf(v + b[0], 0.f);
}

// ---------------- host side ----------------
static void gemm_fp32(hipStream_t s, const float* A, const float* W, const float* bias,
                      float* C, int M, int K, int Nsub, int ldW, int ldC, int col0, int flags) {
  dim3 grid(cdiv(Nsub, 64), cdiv(M, 64));
  k_gemm<<<grid, 256, 0, s>>>(A, W, bias, C, M, K, Nsub, ldW, ldC, col0, flags);
}

static void gemm_mfma(hipStream_t s, const void* A, int lda, int amode,
                      const float* W, int ldW, int wcol0, int K, int Kpad,
                      unsigned short* WtH, unsigned short* WtL,
                      float* C, int M, int Nsub, int ldC, int ccol0,
                      const float* a_s = nullptr, const float* a_d = nullptr,
                      float* als = nullptr, float* ald = nullptr, int lshift = 30) {
  dim3 wg(cdiv(Nsub, 256), Kpad);
  k_buildwt2<<<wg, 256, 0, s>>>(W, ldW, wcol0, Nsub, K, Kpad, WtH, WtL);
  dim3 grid(Nsub / 128, cdiv(M, 64));
  k_mfma_gemm<<<grid, 256, 0, s>>>((const float*)A, lda, amode, K, WtH, WtL, Kpad,
                                   C, M, ldC, ccol0, a_s, a_d, als, ald, lshift);
}

extern "C" void kernel_launch(void* const* d_in, const int* in_sizes, int n_in,
                              void* d_out, int out_size, void* d_ws, size_t ws_size,
                              hipStream_t stream) {
  const float* x = (const float*)d_in[0];
  const int* ei = (const int*)d_in[1];
  const int* batch = (const int*)d_in[2];
  const float* gw1 = (const float*)d_in[3];  const float* gb1 = (const float*)d_in[4];
  const float* gw2 = (const float*)d_in[5];  const float* gb2 = (const float*)d_in[6];
  const float* gw3 = (const float*)d_in[7];  const float* gb3 = (const float*)d_in[8];
  const float* g01g = (const float*)d_in[9];  const float* g01b = (const float*)d_in[10];
  const float* g01m = (const float*)d_in[11]; const float* g01v = (const float*)d_in[12];
  const float* g02g = (const float*)d_in[13]; const float* g02b = (const float*)d_in[14];
  const float* g02m = (const float*)d_in[15]; const float* g02v = (const float*)d_in[16];
  const float* g03g = (const float*)d_in[17]; const float* g03b = (const float*)d_in[18];
  const float* g03m = (const float*)d_in[19]; const float* g03v = (const float*)d_in[20];
  const float* g11g = (const float*)d_in[21]; const float* g11b = (const float*)d_in[22];
  const float* g11m = (const float*)d_in[23]; const float* g11v = (const float*)d_in[24];
  const float* g12g = (const float*)d_in[25]; const float* g12b = (const float*)d_in[26];
  const float* g12m = (const float*)d_in[27]; const float* g12v = (const float*)d_in[28];
  const float* g13g = (const float*)d_in[29]; const float* g13b = (const float*)d_in[30];
  const float* g13m = (const float*)d_in[31]; const float* g13v = (const float*)d_in[32];
  const float* aw1 = (const float*)d_in[33]; const float* as1 = (const float*)d_in[34];
  const float* ad1 = (const float*)d_in[35]; const float* ab1 = (const float*)d_in[36];
  const float* aw2 = (const float*)d_in[37]; const float* as2 = (const float*)d_in[38];
  const float* ad2 = (const float*)d_in[39]; const float* ab2 = (const float*)d_in[40];
  const float* aw3 = (const float*)d_in[41]; const float* as3 = (const float*)d_in[42];
  const float* ad3 = (const float*)d_in[43]; const float* ab3 = (const float*)d_in[44];
  const float* f1w = (const float*)d_in[45]; const float* f1b = (const float*)d_in[46];
  const float* f2w = (const float*)d_in[47]; const float* f2b = (const float*)d_in[48];
  const float* f3w = (const float*)d_in[49]; const float* f3b = (const float*)d_in[50];

  const int* src = ei;
  const int* dst = ei + N_EDGES;

  // ---- workspace carve: exactly round-2's proven 239.456 MB ----
  size_t need = 0;
  need += (size_t)N_NODES * 768;   // OUTP (packed-split activations)
  need += (size_t)N_NODES * 384;   // H (fp32 GEMM out)
  need += (size_t)N_NODES;         // dinv
  need += (size_t)N_NODES * 6;     // als3 + ald3 (head-major; degi/cursor alias)
  need += (size_t)N_NODES + 1;     // rowptr
  need += (size_t)N_EDGES;         // csr_src
  need += (size_t)N_GRAPHS * (512 + 256 + 64);  // pooled + fc1/fc2 (Wt planes alias fc)
  if (ws_size < need * sizeof(float)) return;  // clean-fail guard

  float* wp = (float*)d_ws;
  unsigned* OUTP = (unsigned*)wp; wp += (size_t)N_NODES * 768;
  float* H = wp;       wp += (size_t)N_NODES * 384;
  float* dinv = wp;    wp += N_NODES;
  float* als3 = wp;    wp += (size_t)N_NODES * 3;
  float* ald3 = wp;    wp += (size_t)N_NODES * 3;
  int* rowptr = (int*)wp;  wp += N_NODES + 1;
  int* csr_src = (int*)wp; wp += N_EDGES;
  float* pooled = wp; wp += (size_t)N_GRAPHS * 512;
  float* fc1 = wp;    wp += (size_t)N_GRAPHS * 256;
  float* fc2 = wp;    wp += (size_t)N_GRAPHS * 64;
  int* degi = (int*)als3;
  int* cursor = (int*)ald3;
  // Wt planes (max 384*768 shorts each = 576 KB; rounded slot 393216 shorts)
  // alias fc1+fc2 (640000 words = 2.56 MB); last use precedes first fc write.
  unsigned short* WtH = (unsigned short*)fc1;
  unsigned short* WtL = WtH + 393216;

  // ---- CSR build (once) ----
  k_zero_i<<<cdiv(N_NODES, 256), 256, 0, stream>>>(degi, N_NODES);
  k_deg<<<cdiv(N_EDGES, 256), 256, 0, stream>>>(degi, dst, N_EDGES);
  k_dinv<<<cdiv(N_NODES, 256), 256, 0, stream>>>(degi, dinv, N_NODES);
  k_scan<<<1, 1024, 0, stream>>>(degi, rowptr, cursor, N_NODES);
  k_csr_scatter<<<cdiv(N_EDGES, 256), 256, 0, stream>>>(src, dst, rowptr, cursor, csr_src, N_EDGES);
  k_zero<<<cdiv((long long)N_GRAPHS * 512, 256), 256, 0, stream>>>(pooled, (long long)N_GRAPHS * 512);

  const int nodeWaveGrid = cdiv((long long)N_NODES * 64, 256);

  // ---- GCN path ----
  struct { const float *w, *bias, *g, *b, *m, *v; int F; } gcn[3] = {
    {gw1, gb1, g01g, g01b, g01m, g01v, 256},
    {gw2, gb2, g02g, g02b, g02m, g02v, 128},
    {gw3, gb3, g03g, g03b, g03m, g03v, 128}};
  int gF = F_IN;
  for (int l = 0; l < 3; l++) {
    int F = gcn[l].F;
    if (l == 0)
      gemm_mfma(stream, x, F_IN, 0, gcn[l].w, F, 0, F_IN, 384, WtH, WtL, H, N_NODES, F, F, 0);
    else
      gemm_mfma(stream, OUTP, gF, 1, gcn[l].w, F, 0, gF, gF, WtH, WtL, H, N_NODES, F, F, 0);
    if (F == 256)
      k_gcn_fused<4><<<nodeWaveGrid, 256, 0, stream>>>(H, dinv, rowptr, csr_src,
          gcn[l].bias, gcn[l].g, gcn[l].b, gcn[l].m, gcn[l].v, OUTP, N_NODES, F);
    else
      k_gcn_fused<2><<<nodeWaveGrid, 256, 0, stream>>>(H, dinv, rowptr, csr_src,
          gcn[l].bias, gcn[l].g, gcn[l].b, gcn[l].m, gcn[l].v, OUTP, N_NODES, F);
    gF = F;
  }
  k_pool_add<<<cdiv((long long)N_NODES * 128, 256), 256, 0, stream>>>(pooled, OUTP, batch, N_NODES, 128, 0);

  // ---- GAT1: input x, C=256, per-head GEMM (logits fused) + fused agg ----
  {
    int C = 256, HC = 768;
    for (int hh = 0; hh < 3; hh++) {
      k_zero<<<cdiv((long long)N_NODES * 6, 256), 256, 0, stream>>>(als3, (long long)N_NODES * 6);
      gemm_mfma(stream, x, F_IN, 0, aw1, HC, hh * C, F_IN, 384, WtH, WtL, H, N_NODES, C, C, 0,
                as1 + hh * C, ad1 + hh * C, als3, ald3, 30);
      k_gat_fused<4><<<nodeWaveGrid, 256, 0, stream>>>(H, C, als3, ald3, rowptr, csr_src,
          ab1, g11g, g11b, g11m, g11v, OUTP, HC, hh * C, N_NODES);
    }
  }

  // ---- GAT2 & GAT3: one GEMM (3-head logits fused), merged 3-head agg ----
  struct { const float *w, *s, *d, *bias, *g, *b, *m, *v; int K; } gat[2] = {
    {aw2, as2, ad2, ab2, g12g, g12b, g12m, g12v, 768},
    {aw3, as3, ad3, ab3, g13g, g13b, g13m, g13v, 384}};
  for (int l = 0; l < 2; l++) {
    k_zero<<<cdiv((long long)N_NODES * 6, 256), 256, 0, stream>>>(als3, (long long)N_NODES * 6);
    gemm_mfma(stream, OUTP, gat[l].K, 1, gat[l].w, 384, 0, gat[l].K, gat[l].K, WtH, WtL,
              H, N_NODES, 384, 384, 0, gat[l].s, gat[l].d, als3, ald3, 7);
    k_gat_fused3<<<nodeWaveGrid, 256, 0, stream>>>(H, als3, ald3, rowptr, csr_src,
        gat[l].bias, gat[l].g, gat[l].b, gat[l].m, gat[l].v, OUTP, N_NODES);
  }
  k_pool_add<<<cdiv((long long)N_NODES * 384, 256), 256, 0, stream>>>(pooled, OUTP, batch, N_NODES, 384, 128);

  // ---- FC head ----
  gemm_fp32(stream, pooled, f1w, f1b, fc1, N_GRAPHS, 512, 256, 256, 256, 0, 3);
  gemm_fp32(stream, fc1, f2w, f2b, fc2, N_GRAPHS, 256, 64, 64, 64, 0, 3);
  k_fc3<<<cdiv((long long)N_GRAPHS * 64, 256), 256, 0, stream>>>(fc2, f3w, f3b, (float*)d_out, N_GRAPHS);
}